// Round 1
// baseline (263.141 us; speedup 1.0000x reference)
//
#include <hip/hip_runtime.h>
#include <hip/hip_bf16.h>
#include <hip/hip_fp16.h>

// Problem constants (match reference)
#define B_     8
#define L_     4096
#define DIN    256
#define DOUT   256
#define NGATE  1536   // 3*DOUT*2 dirs
#define KDIM   768    // 3*DIN (im2col window)
#define LP     (L_ + 2)
#define CHUNK  64
#define NCHUNK (L_ / CHUNK)

typedef short  short8  __attribute__((ext_vector_type(8)));
typedef __bf16 bf16x8  __attribute__((ext_vector_type(8)));
typedef float  floatx4 __attribute__((ext_vector_type(4)));

__device__ __forceinline__ float fast_sigmoid(float x) {
    return __builtin_amdgcn_rcpf(1.f + __expf(-x));
}
__device__ __forceinline__ float fast_tanh(float x) {
    // tanh(x) = 1 - 2/(e^{2x}+1); exp->inf gives 1, exp->0 gives -1. OK.
    return 1.f - 2.f * __builtin_amdgcn_rcpf(1.f + __expf(2.f * x));
}
__device__ __forceinline__ unsigned short f2bf(float x) {
    unsigned u = __float_as_uint(x);
    u += 0x7FFF + ((u >> 16) & 1);   // RNE
    return (unsigned short)(u >> 16);
}

// ---------------------------------------------------------------------------
// prep_x: cast input [B,L,256] f32 -> bf16 with one zero row of padding on
// each end of every batch: Xp[b][r][c], r in [0, L+2); r==0 and r==L+1 zero.
// Window for output t is Xp rows t..t+2 (contiguous 768 bf16).
__global__ void prep_x(const float* __restrict__ x, unsigned short* __restrict__ Xp) {
    int idx = blockIdx.x * 256 + threadIdx.x;     // one thread per 4 elements
    int row = idx >> 6;                            // 64 float4 per row
    if (row >= B_ * LP) return;
    int c4 = (idx & 63) << 2;
    int b = row / LP, r = row - b * LP;
    float4 v = make_float4(0.f, 0.f, 0.f, 0.f);
    if (r >= 1 && r <= L_) {
        v = *(const float4*)(x + ((size_t)(b * L_ + (r - 1))) * DIN + c4);
    }
    ushort4 o = make_ushort4(f2bf(v.x), f2bf(v.y), f2bf(v.z), f2bf(v.w));
    *(ushort4*)(Xp + (size_t)row * DIN + c4) = o;
}

// ---------------------------------------------------------------------------
// prep_w: repack W[oc][ic][k] (fwd then bwd stacked on oc) into
// Wc[n][k*256+ic] bf16, n in [0,1536); plus combined bias bc[1536] f32.
__global__ void prep_w(const float* __restrict__ Wf, const float* __restrict__ bf_,
                       const float* __restrict__ Wb, const float* __restrict__ bb,
                       unsigned short* __restrict__ Wc, float* __restrict__ bc) {
    int gid = blockIdx.x * 256 + threadIdx.x;
    if (gid < NGATE) {
        bc[gid] = (gid < 768) ? bf_[gid] : bb[gid - 768];
    }
    if (gid >= NGATE * KDIM) return;
    int n = gid / KDIM, k = gid - n * KDIM;
    int s = k >> 8, ic = k & 255;
    const float* W = (n < 768) ? Wf : Wb;
    int oc = (n < 768) ? n : n - 768;
    float v = W[(size_t)oc * KDIM + ic * 3 + s];
    Wc[(size_t)n * KDIM + k] = f2bf(v);
}

// ---------------------------------------------------------------------------
// gemm_gates: gates[b][t][n] = act( window(b,t) . Wc[n][:] + bc[n] )
// 128x128 block tile, BK=64, bf16 16x16x32 MFMA, XOR-swizzled LDS (8-short
// granule) so ds_read_b128 fragment reads are 2-way (free) not 8-way.
// Activation fused: n-class (n>>8)%3: 0->sigmoid(f) 1->sigmoid(o) 2->tanh(z).
// Output stored fp16 (magnitudes <=1, abs err <=5e-4).
__launch_bounds__(256)
__global__ void gemm_gates(const unsigned short* __restrict__ Xp,
                           const unsigned short* __restrict__ Wc,
                           const float* __restrict__ bc,
                           _Float16* __restrict__ gates) {
    __shared__ unsigned short As[128 * 64];
    __shared__ unsigned short Bs[128 * 64];
    const int tid  = threadIdx.x;
    const int lane = tid & 63, wave = tid >> 6;
    const int quad = lane >> 4, l16 = lane & 15;
    const int wr = wave >> 1, wcl = wave & 1;
    const int bm = blockIdx.y;
    const int b  = bm >> 5;
    const int t0 = (bm & 31) << 7;
    const int n0 = blockIdx.x << 7;
    const unsigned short* Ab = Xp + (size_t)b * LP * DIN;

    floatx4 acc[4][4];
#pragma unroll
    for (int i = 0; i < 4; i++)
#pragma unroll
        for (int j = 0; j < 4; j++) acc[i][j] = (floatx4)0.f;

    for (int k0 = 0; k0 < KDIM; k0 += 64) {
        const int sh = k0 >> 8;        // time shift 0..2
        const int c0 = k0 & 255;       // column offset within DIN
        // Stage A and B tiles (128 rows x 64 cols bf16) via 16B loads.
#pragma unroll
        for (int p = 0; p < 4; p++) {
            int idx = p * 256 + tid;
            int row = idx >> 3, cg = idx & 7;
            int sg = (cg ^ (row & 7)) << 3;     // XOR swizzle, 8-short granule
            short8 av = *(const short8*)(Ab + (size_t)(t0 + row + sh) * DIN + c0 + cg * 8);
            *(short8*)&As[row * 64 + sg] = av;
            short8 bv = *(const short8*)(Wc + (size_t)(n0 + row) * KDIM + k0 + cg * 8);
            *(short8*)&Bs[row * 64 + sg] = bv;
        }
        __syncthreads();
#pragma unroll
        for (int kk = 0; kk < 2; kk++) {
            const int g0 = kk * 4 + quad;
            short8 af[4], bfr[4];
#pragma unroll
            for (int mi = 0; mi < 4; mi++) {
                int row = wr * 64 + mi * 16 + l16;
                af[mi] = *(const short8*)&As[row * 64 + ((g0 ^ (row & 7)) << 3)];
            }
#pragma unroll
            for (int ni = 0; ni < 4; ni++) {
                int row = wcl * 64 + ni * 16 + l16;
                bfr[ni] = *(const short8*)&Bs[row * 64 + ((g0 ^ (row & 7)) << 3)];
            }
#pragma unroll
            for (int mi = 0; mi < 4; mi++)
#pragma unroll
                for (int ni = 0; ni < 4; ni++)
                    acc[mi][ni] = __builtin_amdgcn_mfma_f32_16x16x32_bf16(
                        __builtin_bit_cast(bf16x8, af[mi]),
                        __builtin_bit_cast(bf16x8, bfr[ni]),
                        acc[mi][ni], 0, 0, 0);
        }
        __syncthreads();
    }

    // Epilogue: bias + activation + fp16 store.
#pragma unroll
    for (int ni = 0; ni < 4; ni++) {
        int col = wcl * 64 + ni * 16 + l16;
        int n = n0 + col;
        float bias = bc[n];
        int cls = (n >> 8) % 3;
#pragma unroll
        for (int mi = 0; mi < 4; mi++) {
#pragma unroll
            for (int rr = 0; rr < 4; rr++) {
                int row = wr * 64 + mi * 16 + quad * 4 + rr;   // C/D: col=lane&15, row=quad*4+reg
                float v = acc[mi][ni][rr] + bias;
                v = (cls == 2) ? fast_tanh(v) : fast_sigmoid(v);
                gates[((size_t)(b * L_ + t0 + row)) * NGATE + n] = (_Float16)v;
            }
        }
    }
}

// ---------------------------------------------------------------------------
// scan_chunks (phase A): per (dir,b,chunk,channel) compute affine composition
// over the chunk: c_out = P * c_in + W  with per-step c = f*c + (1-f)*z.
__global__ void scan_chunks(const _Float16* __restrict__ gates,
                            float* __restrict__ Pb, float* __restrict__ Wb) {
    const int d = threadIdx.x;
    const int s = blockIdx.x, b = blockIdx.y, dir = blockIdx.z;
    const _Float16* gbase = gates + (size_t)(b * L_) * NGATE + dir * 768;
    float P = 1.f, W = 0.f;
    if (dir == 0) {
        int t = s * CHUNK;
        for (int i = 0; i < CHUNK; i++, t++) {
            const _Float16* g = gbase + (size_t)t * NGATE;
            float f = (float)g[d];
            float z = (float)g[512 + d];
            W = f * W + (1.f - f) * z;
            P *= f;
        }
    } else {
        int t = s * CHUNK + CHUNK - 1;
        for (int i = 0; i < CHUNK; i++, t--) {
            const _Float16* g = gbase + (size_t)t * NGATE;
            float f = (float)g[d];
            float z = (float)g[512 + d];
            W = f * W + (1.f - f) * z;
            P *= f;
        }
    }
    size_t o = (((size_t)(dir * B_ + b)) * NCHUNK + s) * DOUT + d;
    Pb[o] = P;
    Wb[o] = W;
}

// ---------------------------------------------------------------------------
// scan_seq (phase B): tiny sequential scan over chunks -> chunk-entry cells.
__global__ void scan_seq(const float* __restrict__ Pb, const float* __restrict__ Wb,
                         float* __restrict__ C0) {
    const int d = threadIdx.x;
    const int dir = blockIdx.x >> 3, b = blockIdx.x & 7;
    const size_t base = ((size_t)(dir * B_ + b)) * NCHUNK * DOUT + d;
    float c = 0.f;
    if (dir == 0) {
        for (int s = 0; s < NCHUNK; s++) {
            size_t o = base + (size_t)s * DOUT;
            C0[o] = c;
            c = Pb[o] * c + Wb[o];
        }
    } else {
        for (int s = NCHUNK - 1; s >= 0; s--) {
            size_t o = base + (size_t)s * DOUT;
            C0[o] = c;
            c = Pb[o] * c + Wb[o];
        }
    }
}

// ---------------------------------------------------------------------------
// scan_final (phase C): replay within chunk from C0, write h = c*o, plus
// last_h / last_c at t = L-1 for each direction.
__global__ void scan_final(const _Float16* __restrict__ gates,
                           const float* __restrict__ C0,
                           float* __restrict__ out) {
    const int d = threadIdx.x;
    const int s = blockIdx.x, b = blockIdx.y, dir = blockIdx.z;
    const _Float16* gbase = gates + (size_t)(b * L_) * NGATE + dir * 768;
    float c = C0[(((size_t)(dir * B_ + b)) * NCHUNK + s) * DOUT + d];
    float* ob = out + (size_t)(b * L_) * (2 * DOUT) + dir * DOUT + d;
    float* lasth = out + (size_t)B_ * L_ * (2 * DOUT);
    float* lastc = lasth + B_ * (2 * DOUT);
    if (dir == 0) {
        int t = s * CHUNK;
        for (int i = 0; i < CHUNK; i++, t++) {
            const _Float16* g = gbase + (size_t)t * NGATE;
            float f = (float)g[d], og = (float)g[256 + d], z = (float)g[512 + d];
            c = f * c + (1.f - f) * z;
            float h = c * og;
            ob[(size_t)t * (2 * DOUT)] = h;
            if (t == L_ - 1) { lasth[b * 2 * DOUT + d] = h; lastc[b * 2 * DOUT + d] = c; }
        }
    } else {
        int t = s * CHUNK + CHUNK - 1;
        for (int i = 0; i < CHUNK; i++, t--) {
            const _Float16* g = gbase + (size_t)t * NGATE;
            float f = (float)g[d], og = (float)g[256 + d], z = (float)g[512 + d];
            c = f * c + (1.f - f) * z;
            float h = c * og;
            ob[(size_t)t * (2 * DOUT)] = h;
            if (t == L_ - 1) { lasth[b * 2 * DOUT + DOUT + d] = h; lastc[b * 2 * DOUT + DOUT + d] = c; }
        }
    }
}

// ---------------------------------------------------------------------------
extern "C" void kernel_launch(void* const* d_in, const int* in_sizes, int n_in,
                              void* d_out, int out_size, void* d_ws, size_t ws_size,
                              hipStream_t stream) {
    const float* x   = (const float*)d_in[0];
    // d_in[1] = lengths (unused by the reference computation)
    const float* Wf  = (const float*)d_in[2];
    const float* bfv = (const float*)d_in[3];
    const float* Wb  = (const float*)d_in[4];
    const float* bbv = (const float*)d_in[5];

    char* ws = (char*)d_ws;
    // Workspace layout (bytes), all 256-aligned:
    //   Xp    bf16  B*(L+2)*256          = 16,785,408
    //   Wc    bf16  1536*768             =  2,359,296
    //   bc    f32   1536                 =      6,144
    //   gates fp16  B*L*1536             = 100,663,296
    //   Pb,Wb,C0 f32 2*8*64*256 each     =  1,048,576 x3
    unsigned short* Xp    = (unsigned short*)(ws);
    unsigned short* Wc    = (unsigned short*)(ws + 16785408);
    float*          bc    = (float*)(ws + 19144704);
    _Float16*       gates = (_Float16*)(ws + 19150848);
    float*          Pb    = (float*)(ws + 119814144);
    float*          Wb2   = (float*)(ws + 120862720);
    float*          C0    = (float*)(ws + 121911296);
    float*          out   = (float*)d_out;

    prep_x<<<(B_ * LP * 64 + 255) / 256, 256, 0, stream>>>(x, Xp);
    prep_w<<<(NGATE * KDIM + 255) / 256, 256, 0, stream>>>(Wf, bfv, Wb, bbv, Wc, bc);
    gemm_gates<<<dim3(NGATE / 128, (B_ * L_) / 128), 256, 0, stream>>>(Xp, Wc, bc, gates);
    scan_chunks<<<dim3(NCHUNK, B_, 2), 256, 0, stream>>>(gates, Pb, Wb2);
    scan_seq<<<16, 256, 0, stream>>>(Pb, Wb2, C0);
    scan_final<<<dim3(NCHUNK, B_, 2), 256, 0, stream>>>(gates, C0, out);
}

// Round 2
// 252.292 us; speedup vs baseline: 1.0430x; 1.0430x over previous
//
#include <hip/hip_runtime.h>
#include <hip/hip_bf16.h>
#include <hip/hip_fp16.h>

// Problem constants (match reference)
#define B_     8
#define L_     4096
#define DIN    256
#define DOUT   256
#define NGATE  1536   // 3*DOUT*2 dirs
#define KDIM   768    // 3*DIN (im2col window)
#define LP     (L_ + 2)
#define CHUNK  64
#define NCHUNK (L_ / CHUNK)

typedef short  short8  __attribute__((ext_vector_type(8)));
typedef __bf16 bf16x8  __attribute__((ext_vector_type(8)));
typedef float  floatx4 __attribute__((ext_vector_type(4)));

__device__ __forceinline__ float fast_sigmoid(float x) {
    return __builtin_amdgcn_rcpf(1.f + __expf(-x));
}
__device__ __forceinline__ float fast_tanh(float x) {
    return 1.f - 2.f * __builtin_amdgcn_rcpf(1.f + __expf(2.f * x));
}
__device__ __forceinline__ unsigned short f2bf(float x) {
    unsigned u = __float_as_uint(x);
    u += 0x7FFF + ((u >> 16) & 1);   // RNE
    return (unsigned short)(u >> 16);
}
// Async global->LDS, 16B per lane. LDS dest = wave-uniform base + lane*16.
__device__ __forceinline__ void gload16(const unsigned short* g, unsigned short* l) {
    __builtin_amdgcn_global_load_lds((const __attribute__((address_space(1))) void*)g,
                                     (__attribute__((address_space(3))) void*)l,
                                     16, 0, 0);
}

// ---------------------------------------------------------------------------
// prep_x: f32 [B,L,256] -> bf16 [B, L+2, 256] with zero rows at both ends.
__global__ void prep_x(const float* __restrict__ x, unsigned short* __restrict__ Xp) {
    int idx = blockIdx.x * 256 + threadIdx.x;
    int row = idx >> 6;
    if (row >= B_ * LP) return;
    int c4 = (idx & 63) << 2;
    int b = row / LP, r = row - b * LP;
    float4 v = make_float4(0.f, 0.f, 0.f, 0.f);
    if (r >= 1 && r <= L_) {
        v = *(const float4*)(x + ((size_t)(b * L_ + (r - 1))) * DIN + c4);
    }
    ushort4 o = make_ushort4(f2bf(v.x), f2bf(v.y), f2bf(v.z), f2bf(v.w));
    *(ushort4*)(Xp + (size_t)row * DIN + c4) = o;
}

// ---------------------------------------------------------------------------
// prep_w: W[oc][ic][k] (fwd,bwd stacked) -> Wc[n][k*256+ic] bf16 + bias f32.
__global__ void prep_w(const float* __restrict__ Wf, const float* __restrict__ bf_,
                       const float* __restrict__ Wb, const float* __restrict__ bb,
                       unsigned short* __restrict__ Wc, float* __restrict__ bc) {
    int gid = blockIdx.x * 256 + threadIdx.x;
    if (gid < NGATE) {
        bc[gid] = (gid < 768) ? bf_[gid] : bb[gid - 768];
    }
    if (gid >= NGATE * KDIM) return;
    int n = gid / KDIM, k = gid - n * KDIM;
    int s = k >> 8, ic = k & 255;
    const float* W = (n < 768) ? Wf : Wb;
    int oc = (n < 768) ? n : n - 768;
    float v = W[(size_t)oc * KDIM + ic * 3 + s];
    Wc[(size_t)n * KDIM + k] = f2bf(v);
}

// ---------------------------------------------------------------------------
// gemm_gates: gates[b][t][n] = act( window(b,t) . Wc[n][:] + bc[n] )
// 128x128 tile, BK=64, 16x16x32 bf16 MFMA. Staging via global_load_lds
// (16B/lane); XOR swizzle realized by permuting the *global source* address
// per lane (LDS dest must be lane-contiguous). XCD-aware block swizzle: each
// XCD gets a contiguous range of 32 m-tiles so its L2 keeps B + its A slice.
__launch_bounds__(256)
__global__ void gemm_gates(const unsigned short* __restrict__ Xp,
                           const unsigned short* __restrict__ Wc,
                           const float* __restrict__ bc,
                           _Float16* __restrict__ gates) {
    __shared__ unsigned short As[128 * 64];
    __shared__ unsigned short Bs[128 * 64];
    const int tid  = threadIdx.x;
    const int lane = tid & 63, wave = tid >> 6;
    const int quad = lane >> 4, l16 = lane & 15;
    const int wr = wave >> 1, wcl = wave & 1;

    // XCD swizzle over 3072 blocks: xcd = flat%8 (round-robin dispatch),
    // each xcd covers m in [xcd*32, xcd*32+32) x all 12 n-tiles.
    int flat = blockIdx.x;
    int xcd  = flat & 7;
    int slot = flat >> 3;                 // 0..383
    int m    = xcd * 32 + slot / 12;      // 0..255 m-tile
    int nblk = slot % 12;
    const int b  = m >> 5;
    const int t0 = (m & 31) << 7;
    const int n0 = nblk << 7;
    const unsigned short* Ab = Xp + (size_t)b * LP * DIN;

    // Per-lane inverse-swizzle source mapping (constant across k-steps):
    // LDS granule G = (wave*4+j)*64 + lane; row=G>>3, sgi=G&7, cg=sgi^(row&7).
    int rowj[4], cgj[4];
#pragma unroll
    for (int j = 0; j < 4; j++) {
        int G = (wave * 4 + j) * 64 + lane;
        rowj[j] = G >> 3;
        cgj[j]  = ((G & 7) ^ (rowj[j] & 7)) * 8;
    }

    floatx4 acc[4][4];
#pragma unroll
    for (int i = 0; i < 4; i++)
#pragma unroll
        for (int j = 0; j < 4; j++) acc[i][j] = (floatx4)0.f;

    for (int k0 = 0; k0 < KDIM; k0 += 64) {
        const int sh = k0 >> 8;        // time shift 0..2
        const int c0 = k0 & 255;       // column offset within DIN
#pragma unroll
        for (int j = 0; j < 4; j++) {
            gload16(Ab + (size_t)(t0 + rowj[j] + sh) * DIN + c0 + cgj[j],
                    &As[(wave * 4 + j) * 512]);
            gload16(Wc + (size_t)(n0 + rowj[j]) * KDIM + k0 + cgj[j],
                    &Bs[(wave * 4 + j) * 512]);
        }
        __syncthreads();   // compiler emits s_waitcnt vmcnt(0) before barrier
#pragma unroll
        for (int kk = 0; kk < 2; kk++) {
            const int g0 = kk * 4 + quad;
            short8 af[4], bfr[4];
#pragma unroll
            for (int mi = 0; mi < 4; mi++) {
                int row = wr * 64 + mi * 16 + l16;
                af[mi] = *(const short8*)&As[row * 64 + ((g0 ^ (row & 7)) << 3)];
            }
#pragma unroll
            for (int ni = 0; ni < 4; ni++) {
                int row = wcl * 64 + ni * 16 + l16;
                bfr[ni] = *(const short8*)&Bs[row * 64 + ((g0 ^ (row & 7)) << 3)];
            }
#pragma unroll
            for (int mi = 0; mi < 4; mi++)
#pragma unroll
                for (int ni = 0; ni < 4; ni++)
                    acc[mi][ni] = __builtin_amdgcn_mfma_f32_16x16x32_bf16(
                        __builtin_bit_cast(bf16x8, af[mi]),
                        __builtin_bit_cast(bf16x8, bfr[ni]),
                        acc[mi][ni], 0, 0, 0);
        }
        __syncthreads();
    }

    // Epilogue: bias + activation + fp16 store.
#pragma unroll
    for (int ni = 0; ni < 4; ni++) {
        int col = wcl * 64 + ni * 16 + l16;
        int n = n0 + col;
        float bias = bc[n];
        int cls = (n >> 8) % 3;
#pragma unroll
        for (int mi = 0; mi < 4; mi++) {
#pragma unroll
            for (int rr = 0; rr < 4; rr++) {
                int row = wr * 64 + mi * 16 + quad * 4 + rr;
                float v = acc[mi][ni][rr] + bias;
                v = (cls == 2) ? fast_tanh(v) : fast_sigmoid(v);
                gates[((size_t)(b * L_ + t0 + row)) * NGATE + n] = (_Float16)v;
            }
        }
    }
}

// ---------------------------------------------------------------------------
// scan_chunks (phase A): per (dir,b,chunk) compute affine composition over
// the chunk: c_out = P*c_in + W. half2: each thread owns 2 channels; one
// block covers 2 chunks. Output interleaved (P,W) for latency-friendly
// phase-B loads.
__global__ void scan_chunks(const __half2* __restrict__ gates2,
                            float2* __restrict__ PW) {
    const int tid = threadIdx.x;
    const int dd = tid & 127, sub = tid >> 7;
    const int s = blockIdx.x * 2 + sub, b = blockIdx.y, dir = blockIdx.z;
    const __half2* gb = gates2 + (size_t)(b * L_) * (NGATE / 2) + dir * 384 + dd;
    float2 P = make_float2(1.f, 1.f), W = make_float2(0.f, 0.f);
    if (dir == 0) {
        int t = s * CHUNK;
        for (int i = 0; i < CHUNK; i++, t++) {
            const __half2* g = gb + (size_t)t * (NGATE / 2);
            float2 f = __half22float2(g[0]);
            float2 z = __half22float2(g[256]);
            W.x = f.x * W.x + (1.f - f.x) * z.x;
            W.y = f.y * W.y + (1.f - f.y) * z.y;
            P.x *= f.x; P.y *= f.y;
        }
    } else {
        int t = s * CHUNK + CHUNK - 1;
        for (int i = 0; i < CHUNK; i++, t--) {
            const __half2* g = gb + (size_t)t * (NGATE / 2);
            float2 f = __half22float2(g[0]);
            float2 z = __half22float2(g[256]);
            W.x = f.x * W.x + (1.f - f.x) * z.x;
            W.y = f.y * W.y + (1.f - f.y) * z.y;
            P.x *= f.x; P.y *= f.y;
        }
    }
    float4 o4 = make_float4(P.x, W.x, P.y, W.y);
    *(float4*)&PW[(((size_t)(dir * 8 + b) * NCHUNK + s) * 256) + 2 * dd] = o4;
}

// ---------------------------------------------------------------------------
// scan_seq (phase B): sequential scan over chunks. Fully unrolled so the 64
// independent float2 loads hoist ahead of the dependent FMA chain.
__global__ void scan_seq(const float2* __restrict__ PW, float* __restrict__ C0) {
    const int c = threadIdx.x;
    const int dir = blockIdx.x >> 3, b = blockIdx.x & 7;
    const size_t base = ((size_t)(dir * 8 + b)) * NCHUNK * 256 + c;
    float cc = 0.f;
    if (dir == 0) {
#pragma unroll
        for (int s = 0; s < NCHUNK; s++) {
            float2 pw = PW[base + (size_t)s * 256];
            C0[base + (size_t)s * 256] = cc;
            cc = pw.x * cc + pw.y;
        }
    } else {
#pragma unroll
        for (int s = NCHUNK - 1; s >= 0; s--) {
            float2 pw = PW[base + (size_t)s * 256];
            C0[base + (size_t)s * 256] = cc;
            cc = pw.x * cc + pw.y;
        }
    }
}

// ---------------------------------------------------------------------------
// scan_final (phase C): replay within chunk from C0; write h = c*o, plus
// last_h / last_c at t = L-1 for each direction.
__global__ void scan_final(const __half2* __restrict__ gates2,
                           const float* __restrict__ C0,
                           float* __restrict__ out) {
    const int tid = threadIdx.x;
    const int dd = tid & 127, sub = tid >> 7;
    const int s = blockIdx.x * 2 + sub, b = blockIdx.y, dir = blockIdx.z;
    const __half2* gb = gates2 + (size_t)(b * L_) * (NGATE / 2) + dir * 384 + dd;
    float2 c = *(const float2*)&C0[(((size_t)(dir * 8 + b) * NCHUNK + s) * 256) + 2 * dd];
    float* ob = out + (size_t)(b * L_) * (2 * DOUT) + dir * DOUT + 2 * dd;
    float* lasth = out + (size_t)B_ * L_ * (2 * DOUT);
    float* lastc = lasth + B_ * (2 * DOUT);
    if (dir == 0) {
        int t = s * CHUNK;
        for (int i = 0; i < CHUNK; i++, t++) {
            const __half2* g = gb + (size_t)t * (NGATE / 2);
            float2 f = __half22float2(g[0]);
            float2 o = __half22float2(g[128]);
            float2 z = __half22float2(g[256]);
            c.x = f.x * c.x + (1.f - f.x) * z.x;
            c.y = f.y * c.y + (1.f - f.y) * z.y;
            float2 h = make_float2(c.x * o.x, c.y * o.y);
            *(float2*)&ob[(size_t)t * (2 * DOUT)] = h;
            if (t == L_ - 1) {
                *(float2*)&lasth[b * 2 * DOUT + 2 * dd] = h;
                *(float2*)&lastc[b * 2 * DOUT + 2 * dd] = c;
            }
        }
    } else {
        int t = s * CHUNK + CHUNK - 1;
        for (int i = 0; i < CHUNK; i++, t--) {
            const __half2* g = gb + (size_t)t * (NGATE / 2);
            float2 f = __half22float2(g[0]);
            float2 o = __half22float2(g[128]);
            float2 z = __half22float2(g[256]);
            c.x = f.x * c.x + (1.f - f.x) * z.x;
            c.y = f.y * c.y + (1.f - f.y) * z.y;
            float2 h = make_float2(c.x * o.x, c.y * o.y);
            *(float2*)&ob[(size_t)t * (2 * DOUT)] = h;
            if (t == L_ - 1) {
                *(float2*)&lasth[b * 2 * DOUT + DOUT + 2 * dd] = h;
                *(float2*)&lastc[b * 2 * DOUT + DOUT + 2 * dd] = c;
            }
        }
    }
}

// ---------------------------------------------------------------------------
extern "C" void kernel_launch(void* const* d_in, const int* in_sizes, int n_in,
                              void* d_out, int out_size, void* d_ws, size_t ws_size,
                              hipStream_t stream) {
    const float* x   = (const float*)d_in[0];
    // d_in[1] = lengths (unused by the reference computation)
    const float* Wf  = (const float*)d_in[2];
    const float* bfv = (const float*)d_in[3];
    const float* Wb  = (const float*)d_in[4];
    const float* bbv = (const float*)d_in[5];

    char* ws = (char*)d_ws;
    // Workspace layout (bytes):
    //   Xp    bf16  B*(L+2)*256          = 16,785,408
    //   Wc    bf16  1536*768             =  2,359,296
    //   bc    f32   1536                 =      6,144
    //   gates fp16  B*L*1536             = 100,663,296
    //   PW    f32x2 2*8*64*256           =  2,097,152
    //   C0    f32   2*8*64*256           =  1,048,576
    unsigned short* Xp    = (unsigned short*)(ws);
    unsigned short* Wc    = (unsigned short*)(ws + 16785408);
    float*          bc    = (float*)(ws + 19144704);
    _Float16*       gates = (_Float16*)(ws + 19150848);
    float2*         PW    = (float2*)(ws + 119814144);
    float*          C0    = (float*)(ws + 121911296);
    float*          out   = (float*)d_out;

    prep_x<<<(B_ * LP * 64 + 255) / 256, 256, 0, stream>>>(x, Xp);
    prep_w<<<(NGATE * KDIM + 255) / 256, 256, 0, stream>>>(Wf, bfv, Wb, bbv, Wc, bc);
    gemm_gates<<<3072, 256, 0, stream>>>(Xp, Wc, bc, gates);
    scan_chunks<<<dim3(NCHUNK / 2, B_, 2), 256, 0, stream>>>((const __half2*)gates, PW);
    scan_seq<<<16, 256, 0, stream>>>(PW, C0);
    scan_final<<<dim3(NCHUNK / 2, B_, 2), 256, 0, stream>>>((const __half2*)gates, C0, out);
}

// Round 3
// 232.525 us; speedup vs baseline: 1.1317x; 1.0850x over previous
//
#include <hip/hip_runtime.h>
#include <hip/hip_bf16.h>
#include <hip/hip_fp16.h>

// Problem constants (match reference)
#define B_     8
#define L_     4096
#define DIN    256
#define DOUT   256
#define NGATE  1536   // 3*DOUT*2 dirs
#define KDIM   768    // 3*DIN (im2col window)
#define LP     (L_ + 2)
#define CHUNK  32
#define NCHUNK (L_ / CHUNK)

typedef short    short8  __attribute__((ext_vector_type(8)));
typedef __bf16   bf16x8  __attribute__((ext_vector_type(8)));
typedef float    floatx4 __attribute__((ext_vector_type(4)));
typedef _Float16 half4   __attribute__((ext_vector_type(4)));

__device__ __forceinline__ float fast_sigmoid(float x) {
    return __builtin_amdgcn_rcpf(1.f + __expf(-x));
}
__device__ __forceinline__ float fast_tanh(float x) {
    return 1.f - 2.f * __builtin_amdgcn_rcpf(1.f + __expf(2.f * x));
}
__device__ __forceinline__ unsigned short f2bf(float x) {
    unsigned u = __float_as_uint(x);
    u += 0x7FFF + ((u >> 16) & 1);   // RNE
    return (unsigned short)(u >> 16);
}
// Async global->LDS, 16B per lane. LDS dest = wave-uniform base + lane*16.
__device__ __forceinline__ void gload16(const unsigned short* g, unsigned short* l) {
    __builtin_amdgcn_global_load_lds((const __attribute__((address_space(1))) void*)g,
                                     (__attribute__((address_space(3))) void*)l,
                                     16, 0, 0);
}

// ---------------------------------------------------------------------------
// prep_x: f32 [B,L,256] -> bf16 [B, L+2, 256] with zero rows at both ends.
__global__ void prep_x(const float* __restrict__ x, unsigned short* __restrict__ Xp) {
    int idx = blockIdx.x * 256 + threadIdx.x;
    int row = idx >> 6;
    if (row >= B_ * LP) return;
    int c4 = (idx & 63) << 2;
    int b = row / LP, r = row - b * LP;
    float4 v = make_float4(0.f, 0.f, 0.f, 0.f);
    if (r >= 1 && r <= L_) {
        v = *(const float4*)(x + ((size_t)(b * L_ + (r - 1))) * DIN + c4);
    }
    ushort4 o = make_ushort4(f2bf(v.x), f2bf(v.y), f2bf(v.z), f2bf(v.w));
    *(ushort4*)(Xp + (size_t)row * DIN + c4) = o;
}

// ---------------------------------------------------------------------------
// prep_w: W[oc][ic][k] (fwd,bwd stacked) -> Wc[n][k*256+ic] bf16 + bias f32.
__global__ void prep_w(const float* __restrict__ Wf, const float* __restrict__ bf_,
                       const float* __restrict__ Wb, const float* __restrict__ bb,
                       unsigned short* __restrict__ Wc, float* __restrict__ bc) {
    int gid = blockIdx.x * 256 + threadIdx.x;
    if (gid < NGATE) {
        bc[gid] = (gid < 768) ? bf_[gid] : bb[gid - 768];
    }
    if (gid >= NGATE * KDIM) return;
    int n = gid / KDIM, k = gid - n * KDIM;
    int s = k >> 8, ic = k & 255;
    const float* W = (n < 768) ? Wf : Wb;
    int oc = (n < 768) ? n : n - 768;
    float v = W[(size_t)oc * KDIM + ic * 3 + s];
    Wc[(size_t)n * KDIM + k] = f2bf(v);
}

// ---------------------------------------------------------------------------
// gemm_gates: 256x128 block tile, 512 threads (8 waves, each 64x64), BK=64,
// bf16 16x16x32 MFMA. Staging via global_load_lds 16B/lane with the XOR
// swizzle realized by permuting the *global source* address per lane.
// XCD-aware swizzle: each XCD owns 16 contiguous m-tiles x all 12 n-tiles.
__launch_bounds__(512)
__global__ void gemm_gates(const unsigned short* __restrict__ Xp,
                           const unsigned short* __restrict__ Wc,
                           const float* __restrict__ bc,
                           _Float16* __restrict__ gates) {
    __shared__ unsigned short As[256 * 64];   // 32 KB
    __shared__ unsigned short Bs[128 * 64];   // 16 KB
    const int tid  = threadIdx.x;
    const int lane = tid & 63, wave = tid >> 6;     // wave 0..7
    const int quad = lane >> 4, l16 = lane & 15;
    const int wr = wave >> 1, wcl = wave & 1;       // wr 0..3 (m), wcl 0..1 (n)

    int flat = blockIdx.x;                 // 0..1535
    int xcd  = flat & 7;
    int slot = flat >> 3;                  // 0..191
    int m    = xcd * 16 + slot / 12;       // 0..127 m-tile (256 rows each)
    int nblk = slot % 12;
    const int b  = m >> 4;
    const int t0 = (m & 15) << 8;
    const int n0 = nblk << 7;
    const unsigned short* Ab = Xp + (size_t)b * LP * DIN;

    // Per-lane inverse-swizzle source mapping (constant across k-steps).
    int rowA[4], cgA[4], rowB[2], cgB[2];
#pragma unroll
    for (int j = 0; j < 4; j++) {
        int G = (wave * 4 + j) * 64 + lane;      // A granule 0..2047
        rowA[j] = G >> 3;
        cgA[j]  = ((G & 7) ^ (rowA[j] & 7)) * 8;
    }
#pragma unroll
    for (int j = 0; j < 2; j++) {
        int G = (wave * 2 + j) * 64 + lane;      // B granule 0..1023
        rowB[j] = G >> 3;
        cgB[j]  = ((G & 7) ^ (rowB[j] & 7)) * 8;
    }

    floatx4 acc[4][4];
#pragma unroll
    for (int i = 0; i < 4; i++)
#pragma unroll
        for (int j = 0; j < 4; j++) acc[i][j] = (floatx4)0.f;

    for (int k0 = 0; k0 < KDIM; k0 += 64) {
        const int sh = k0 >> 8;        // time shift 0..2
        const int c0 = k0 & 255;       // column offset within DIN
#pragma unroll
        for (int j = 0; j < 4; j++)
            gload16(Ab + (size_t)(t0 + rowA[j] + sh) * DIN + c0 + cgA[j],
                    &As[(wave * 4 + j) * 512]);
#pragma unroll
        for (int j = 0; j < 2; j++)
            gload16(Wc + (size_t)(n0 + rowB[j]) * KDIM + k0 + cgB[j],
                    &Bs[(wave * 2 + j) * 512]);
        __syncthreads();
#pragma unroll
        for (int kk = 0; kk < 2; kk++) {
            const int g0 = kk * 4 + quad;
            short8 af[4], bfr[4];
#pragma unroll
            for (int mi = 0; mi < 4; mi++) {
                int row = wr * 64 + mi * 16 + l16;
                af[mi] = *(const short8*)&As[row * 64 + ((g0 ^ (row & 7)) << 3)];
            }
#pragma unroll
            for (int ni = 0; ni < 4; ni++) {
                int row = wcl * 64 + ni * 16 + l16;
                bfr[ni] = *(const short8*)&Bs[row * 64 + ((g0 ^ (row & 7)) << 3)];
            }
#pragma unroll
            for (int mi = 0; mi < 4; mi++)
#pragma unroll
                for (int ni = 0; ni < 4; ni++)
                    acc[mi][ni] = __builtin_amdgcn_mfma_f32_16x16x32_bf16(
                        __builtin_bit_cast(bf16x8, af[mi]),
                        __builtin_bit_cast(bf16x8, bfr[ni]),
                        acc[mi][ni], 0, 0, 0);
        }
        __syncthreads();
    }

    // Epilogue: bias + activation + fp16 store.
#pragma unroll
    for (int ni = 0; ni < 4; ni++) {
        int col = wcl * 64 + ni * 16 + l16;
        int n = n0 + col;
        float bias = bc[n];
        int cls = (n >> 8) % 3;
#pragma unroll
        for (int mi = 0; mi < 4; mi++) {
#pragma unroll
            for (int rr = 0; rr < 4; rr++) {
                int row = wr * 64 + mi * 16 + quad * 4 + rr;
                float v = acc[mi][ni][rr] + bias;
                v = (cls == 2) ? fast_tanh(v) : fast_sigmoid(v);
                gates[((size_t)(b * L_ + t0 + row)) * NGATE + n] = (_Float16)v;
            }
        }
    }
}

// ---------------------------------------------------------------------------
// scan_chunks (phase A): per (dir,b,chunk) affine composition over CHUNK=32
// steps: c_out = P*c_in + W. Each thread owns 4 channels (8B half4 loads);
// each wave owns one chunk; block = 4 chunks.
__global__ void scan_chunks(const _Float16* __restrict__ gates,
                            float2* __restrict__ PW) {
    const int tid = threadIdx.x;
    const int cg = tid & 63, sub = tid >> 6;       // cg: channel group of 4
    const int s = blockIdx.x * 4 + sub, b = blockIdx.y, dir = blockIdx.z;
    const _Float16* gb = gates + (size_t)(b * L_) * NGATE + dir * 768 + cg * 4;
    float P[4] = {1.f, 1.f, 1.f, 1.f}, W[4] = {0.f, 0.f, 0.f, 0.f};
    if (dir == 0) {
        int t = s * CHUNK;
#pragma unroll 8
        for (int i = 0; i < CHUNK; i++, t++) {
            half4 f4 = *(const half4*)(gb + (size_t)t * NGATE);
            half4 z4 = *(const half4*)(gb + (size_t)t * NGATE + 512);
#pragma unroll
            for (int u = 0; u < 4; u++) {
                float f = (float)f4[u], z = (float)z4[u];
                W[u] = f * W[u] + (1.f - f) * z;
                P[u] *= f;
            }
        }
    } else {
        int t = s * CHUNK + CHUNK - 1;
#pragma unroll 8
        for (int i = 0; i < CHUNK; i++, t--) {
            half4 f4 = *(const half4*)(gb + (size_t)t * NGATE);
            half4 z4 = *(const half4*)(gb + (size_t)t * NGATE + 512);
#pragma unroll
            for (int u = 0; u < 4; u++) {
                float f = (float)f4[u], z = (float)z4[u];
                W[u] = f * W[u] + (1.f - f) * z;
                P[u] *= f;
            }
        }
    }
    float2* p = &PW[(((size_t)(dir * 8 + b)) * NCHUNK + s) * 256 + cg * 4];
    float4 o0 = make_float4(P[0], W[0], P[1], W[1]);
    float4 o1 = make_float4(P[2], W[2], P[3], W[3]);
    *(float4*)&p[0] = o0;
    *(float4*)&p[2] = o1;
}

// ---------------------------------------------------------------------------
// scan_seq (phase B): sequential scan over NCHUNK=128 chunks.
__global__ void scan_seq(const float2* __restrict__ PW, float* __restrict__ C0) {
    const int c = threadIdx.x;
    const int dir = blockIdx.x >> 3, b = blockIdx.x & 7;
    const size_t base = ((size_t)(dir * 8 + b)) * NCHUNK * 256 + c;
    float cc = 0.f;
    if (dir == 0) {
#pragma unroll 16
        for (int s = 0; s < NCHUNK; s++) {
            float2 pw = PW[base + (size_t)s * 256];
            C0[base + (size_t)s * 256] = cc;
            cc = pw.x * cc + pw.y;
        }
    } else {
#pragma unroll 16
        for (int s = NCHUNK - 1; s >= 0; s--) {
            float2 pw = PW[base + (size_t)s * 256];
            C0[base + (size_t)s * 256] = cc;
            cc = pw.x * cc + pw.y;
        }
    }
}

// ---------------------------------------------------------------------------
// scan_final (phase C): replay within chunk from C0; h = c*o to out (float4
// stores), plus last_h/last_c at t = L-1.
__global__ void scan_final(const _Float16* __restrict__ gates,
                           const float* __restrict__ C0,
                           float* __restrict__ out) {
    const int tid = threadIdx.x;
    const int cg = tid & 63, sub = tid >> 6;
    const int s = blockIdx.x * 4 + sub, b = blockIdx.y, dir = blockIdx.z;
    const _Float16* gb = gates + (size_t)(b * L_) * NGATE + dir * 768 + cg * 4;
    float4 c = *(const float4*)&C0[(((size_t)(dir * 8 + b)) * NCHUNK + s) * 256 + cg * 4];
    float* ob = out + (size_t)(b * L_) * (2 * DOUT) + dir * DOUT + cg * 4;
    float* lasth = out + (size_t)B_ * L_ * (2 * DOUT);
    float* lastc = lasth + B_ * (2 * DOUT);
    const int step = (dir == 0) ? 1 : -1;
    int t = (dir == 0) ? s * CHUNK : s * CHUNK + CHUNK - 1;
#pragma unroll 8
    for (int i = 0; i < CHUNK; i++, t += step) {
        half4 f4 = *(const half4*)(gb + (size_t)t * NGATE);
        half4 o4 = *(const half4*)(gb + (size_t)t * NGATE + 256);
        half4 z4 = *(const half4*)(gb + (size_t)t * NGATE + 512);
        float4 h;
        {
            float f = (float)f4[0], z = (float)z4[0];
            c.x = f * c.x + (1.f - f) * z; h.x = c.x * (float)o4[0];
            f = (float)f4[1]; z = (float)z4[1];
            c.y = f * c.y + (1.f - f) * z; h.y = c.y * (float)o4[1];
            f = (float)f4[2]; z = (float)z4[2];
            c.z = f * c.z + (1.f - f) * z; h.z = c.z * (float)o4[2];
            f = (float)f4[3]; z = (float)z4[3];
            c.w = f * c.w + (1.f - f) * z; h.w = c.w * (float)o4[3];
        }
        *(float4*)&ob[(size_t)t * (2 * DOUT)] = h;
        if (t == L_ - 1) {
            *(float4*)&lasth[b * 2 * DOUT + dir * DOUT + cg * 4] = h;
            *(float4*)&lastc[b * 2 * DOUT + dir * DOUT + cg * 4] = c;
        }
    }
}

// ---------------------------------------------------------------------------
extern "C" void kernel_launch(void* const* d_in, const int* in_sizes, int n_in,
                              void* d_out, int out_size, void* d_ws, size_t ws_size,
                              hipStream_t stream) {
    const float* x   = (const float*)d_in[0];
    // d_in[1] = lengths (unused by the reference computation)
    const float* Wf  = (const float*)d_in[2];
    const float* bfv = (const float*)d_in[3];
    const float* Wb  = (const float*)d_in[4];
    const float* bbv = (const float*)d_in[5];

    char* ws = (char*)d_ws;
    // Workspace layout (bytes):
    //   Xp    bf16  B*(L+2)*256          = 16,785,408   (offset 0; dead after GEMM)
    //   Wc    bf16  1536*768             =  2,359,296   (offset 16,785,408)
    //   bc    f32   1536                 =      6,144   (offset 19,144,704)
    //   gates fp16  B*L*1536             = 100,663,296  (offset 19,150,848)
    //   PW    f32x2 2*8*128*256          =  4,194,304   (offset 0 — reuses Xp)
    //   C0    f32   2*8*128*256          =  2,097,152   (offset 4,194,304)
    unsigned short* Xp    = (unsigned short*)(ws);
    unsigned short* Wc    = (unsigned short*)(ws + 16785408);
    float*          bc    = (float*)(ws + 19144704);
    _Float16*       gates = (_Float16*)(ws + 19150848);
    float2*         PW    = (float2*)(ws);              // reuse Xp region
    float*          C0    = (float*)(ws + 4194304);     // reuse Xp region
    float*          out   = (float*)d_out;

    prep_x<<<(B_ * LP * 64 + 255) / 256, 256, 0, stream>>>(x, Xp);
    prep_w<<<(NGATE * KDIM + 255) / 256, 256, 0, stream>>>(Wf, bfv, Wb, bbv, Wc, bc);
    gemm_gates<<<1536, 512, 0, stream>>>(Xp, Wc, bc, gates);
    scan_chunks<<<dim3(NCHUNK / 4, B_, 2), 256, 0, stream>>>(gates, PW);
    scan_seq<<<16, 256, 0, stream>>>(PW, C0);
    scan_final<<<dim3(NCHUNK / 4, B_, 2), 256, 0, stream>>>(gates, C0, out);
}

// Round 4
// 215.838 us; speedup vs baseline: 1.2192x; 1.0773x over previous
//
#include <hip/hip_runtime.h>
#include <hip/hip_bf16.h>
#include <hip/hip_fp16.h>

// Problem constants (match reference)
#define B_     8
#define L_     4096
#define DIN    256
#define DOUT   256
#define NGATE  1536   // 3*DOUT*2 dirs
#define KDIM   768    // 3*DIN (im2col window)
#define LP     (L_ + 2)
#define CHUNK  32
#define NCHUNK (L_ / CHUNK)

typedef short    short8  __attribute__((ext_vector_type(8)));
typedef __bf16   bf16x8  __attribute__((ext_vector_type(8)));
typedef float    floatx4 __attribute__((ext_vector_type(4)));
typedef _Float16 half4   __attribute__((ext_vector_type(4)));

__device__ __forceinline__ float fast_sigmoid(float x) {
    return __builtin_amdgcn_rcpf(1.f + __expf(-x));
}
__device__ __forceinline__ float fast_tanh(float x) {
    return 1.f - 2.f * __builtin_amdgcn_rcpf(1.f + __expf(2.f * x));
}
__device__ __forceinline__ unsigned short f2bf(float x) {
    unsigned u = __float_as_uint(x);
    u += 0x7FFF + ((u >> 16) & 1);   // RNE
    return (unsigned short)(u >> 16);
}
// Async global->LDS, 16B per lane. LDS dest = wave-uniform base + lane*16.
__device__ __forceinline__ void gload16(const unsigned short* g, unsigned short* l) {
    __builtin_amdgcn_global_load_lds((const __attribute__((address_space(1))) void*)g,
                                     (__attribute__((address_space(3))) void*)l,
                                     16, 0, 0);
}

// Native-layout gates addressing ------------------------------------------
// gates fp16, flat unit index:
//   A(t,n) = ((bm*12 + nblk)*8 + (wr*2+wcl))*4096 + (ni*4+mi)*256
//            + (quad*16 + l16)*4 + rr
// where (for batch b, time t, gate column n):
//   bm = b*16 + (t>>8), wr = (t>>6)&3, mi = (t>>4)&3, quad = (t>>2)&3, rr = t&3
//   nblk = n>>7, wcl = (n>>6)&1, ni = (n>>4)&3, l16 = n&15
// This is exactly the MFMA C-layout of gemm_gates, so the epilogue stores a
// lane's 4 accumulators (4 consecutive t, one n) as one contiguous 8B chunk.
__device__ __forceinline__ int gate_noff(int n) {
    return (n >> 7) * 32768 + ((n >> 6) & 1) * 4096 + ((n >> 4) & 3) * 1024 + (n & 15) * 4;
}
__device__ __forceinline__ int gate_toff(int b, int t) {
    return (b * 16 + (t >> 8)) * 393216 + ((t >> 6) & 3) * 8192
         + ((t >> 4) & 3) * 256 + ((t >> 2) & 3) * 64;
}

// ---------------------------------------------------------------------------
// prep_all: fused prep_x (blocks [0,NXB)) + prep_w (blocks [NXB,..)).
#define NXB ((B_ * LP * 64 + 255) / 256)
#define NWB ((NGATE * KDIM + 255) / 256)
__global__ void prep_all(const float* __restrict__ x, unsigned short* __restrict__ Xp,
                         const float* __restrict__ Wf, const float* __restrict__ bf_,
                         const float* __restrict__ Wb, const float* __restrict__ bb,
                         unsigned short* __restrict__ Wc, float* __restrict__ bc) {
    if (blockIdx.x < NXB) {
        int idx = blockIdx.x * 256 + threadIdx.x;
        int row = idx >> 6;
        if (row >= B_ * LP) return;
        int c4 = (idx & 63) << 2;
        int b = row / LP, r = row - b * LP;
        float4 v = make_float4(0.f, 0.f, 0.f, 0.f);
        if (r >= 1 && r <= L_) {
            v = *(const float4*)(x + ((size_t)(b * L_ + (r - 1))) * DIN + c4);
        }
        ushort4 o = make_ushort4(f2bf(v.x), f2bf(v.y), f2bf(v.z), f2bf(v.w));
        *(ushort4*)(Xp + (size_t)row * DIN + c4) = o;
    } else {
        int gid = (blockIdx.x - NXB) * 256 + threadIdx.x;
        if (gid < NGATE) {
            bc[gid] = (gid < 768) ? bf_[gid] : bb[gid - 768];
        }
        if (gid >= NGATE * KDIM) return;
        int n = gid / KDIM, k = gid - n * KDIM;
        int s = k >> 8, ic = k & 255;
        const float* W = (n < 768) ? Wf : Wb;
        int oc = (n < 768) ? n : n - 768;
        float v = W[(size_t)oc * KDIM + ic * 3 + s];
        Wc[(size_t)n * KDIM + k] = f2bf(v);
    }
}

// ---------------------------------------------------------------------------
// gemm_gates: 256x128 tile, 512 threads (8 waves), BK=64, 16x16x32 bf16 MFMA.
// global_load_lds staging with source-side XOR swizzle. Epilogue stores in
// MFMA-native layout: one 8B store per (ni,mi) per lane -> 512B contiguous
// per instruction, full-line writes (fixes the 2x write amplification seen
// with scalar fp16 stores in the [t][n] layout).
__launch_bounds__(512)
__global__ void gemm_gates(const unsigned short* __restrict__ Xp,
                           const unsigned short* __restrict__ Wc,
                           const float* __restrict__ bc,
                           _Float16* __restrict__ gates) {
    __shared__ unsigned short As[256 * 64];   // 32 KB
    __shared__ unsigned short Bs[128 * 64];   // 16 KB
    const int tid  = threadIdx.x;
    const int lane = tid & 63, wave = tid >> 6;     // wave 0..7
    const int quad = lane >> 4, l16 = lane & 15;
    const int wr = wave >> 1, wcl = wave & 1;       // wr 0..3 (m), wcl 0..1 (n)

    int flat = blockIdx.x;                 // 0..1535
    int xcd  = flat & 7;
    int slot = flat >> 3;                  // 0..191
    int bm   = xcd * 16 + slot / 12;       // 0..127 m-tile (256 rows each)
    int nblk = slot % 12;
    const int b  = bm >> 4;
    const int t0 = (bm & 15) << 8;
    const int n0 = nblk << 7;
    const unsigned short* Ab = Xp + (size_t)b * LP * DIN;

    // Per-lane inverse-swizzle source mapping (constant across k-steps).
    int rowA[4], cgA[4], rowB[2], cgB[2];
#pragma unroll
    for (int j = 0; j < 4; j++) {
        int G = (wave * 4 + j) * 64 + lane;      // A granule 0..2047
        rowA[j] = G >> 3;
        cgA[j]  = ((G & 7) ^ (rowA[j] & 7)) * 8;
    }
#pragma unroll
    for (int j = 0; j < 2; j++) {
        int G = (wave * 2 + j) * 64 + lane;      // B granule 0..1023
        rowB[j] = G >> 3;
        cgB[j]  = ((G & 7) ^ (rowB[j] & 7)) * 8;
    }

    floatx4 acc[4][4];
#pragma unroll
    for (int i = 0; i < 4; i++)
#pragma unroll
        for (int j = 0; j < 4; j++) acc[i][j] = (floatx4)0.f;

    for (int k0 = 0; k0 < KDIM; k0 += 64) {
        const int sh = k0 >> 8;        // time shift 0..2
        const int c0 = k0 & 255;       // column offset within DIN
#pragma unroll
        for (int j = 0; j < 4; j++)
            gload16(Ab + (size_t)(t0 + rowA[j] + sh) * DIN + c0 + cgA[j],
                    &As[(wave * 4 + j) * 512]);
#pragma unroll
        for (int j = 0; j < 2; j++)
            gload16(Wc + (size_t)(n0 + rowB[j]) * KDIM + k0 + cgB[j],
                    &Bs[(wave * 2 + j) * 512]);
        __syncthreads();
#pragma unroll
        for (int kk = 0; kk < 2; kk++) {
            const int g0 = kk * 4 + quad;
            short8 af[4], bfr[4];
#pragma unroll
            for (int mi = 0; mi < 4; mi++) {
                int row = wr * 64 + mi * 16 + l16;
                af[mi] = *(const short8*)&As[row * 64 + ((g0 ^ (row & 7)) << 3)];
            }
#pragma unroll
            for (int ni = 0; ni < 4; ni++) {
                int row = wcl * 64 + ni * 16 + l16;
                bfr[ni] = *(const short8*)&Bs[row * 64 + ((g0 ^ (row & 7)) << 3)];
            }
#pragma unroll
            for (int mi = 0; mi < 4; mi++)
#pragma unroll
                for (int ni = 0; ni < 4; ni++)
                    acc[mi][ni] = __builtin_amdgcn_mfma_f32_16x16x32_bf16(
                        __builtin_bit_cast(bf16x8, af[mi]),
                        __builtin_bit_cast(bf16x8, bfr[ni]),
                        acc[mi][ni], 0, 0, 0);
        }
        __syncthreads();
    }

    // Epilogue: bias + activation, native-layout 8B stores.
    const int cls = ((n0 + wcl * 64) >> 8) % 3;   // wave-uniform gate class
    _Float16* gb = gates + ((size_t)(bm * 12 + nblk) * 8 + wave) * 4096 + lane * 4;
#pragma unroll
    for (int ni = 0; ni < 4; ni++) {
        float bias = bc[n0 + wcl * 64 + ni * 16 + l16];
#pragma unroll
        for (int mi = 0; mi < 4; mi++) {
            half4 hv;
#pragma unroll
            for (int rr = 0; rr < 4; rr++) {
                float v = acc[mi][ni][rr] + bias;
                v = (cls == 2) ? fast_tanh(v) : fast_sigmoid(v);
                hv[rr] = (_Float16)v;
            }
            *(half4*)(gb + (ni * 4 + mi) * 256) = hv;
        }
    }
}

// ---------------------------------------------------------------------------
// scan_chunks (phase A): thread = one channel, block = one (chunk,b,dir).
// Reads f,z in native layout (8B = 4 consecutive t per load), composes the
// chunk affine map c_out = P*c_in + W.
__global__ void scan_chunks(const _Float16* __restrict__ gates,
                            float2* __restrict__ PW) {
    const int d = threadIdx.x;                       // channel 0..255
    const int s = blockIdx.x, b = blockIdx.y, dir = blockIdx.z;
    const int onf = gate_noff(dir * 768 + d);
    const int onz = gate_noff(dir * 768 + 512 + d);
    float P = 1.f, W = 0.f;
    if (dir == 0) {
#pragma unroll
        for (int gi = 0; gi < 8; gi++) {
            int t = s * CHUNK + gi * 4;
            int ot = gate_toff(b, t);
            half4 f4 = *(const half4*)(gates + ot + onf);
            half4 z4 = *(const half4*)(gates + ot + onz);
#pragma unroll
            for (int u = 0; u < 4; u++) {
                float f = (float)f4[u], z = (float)z4[u];
                W = f * W + (1.f - f) * z;
                P *= f;
            }
        }
    } else {
#pragma unroll
        for (int gi = 7; gi >= 0; gi--) {
            int t = s * CHUNK + gi * 4;
            int ot = gate_toff(b, t);
            half4 f4 = *(const half4*)(gates + ot + onf);
            half4 z4 = *(const half4*)(gates + ot + onz);
#pragma unroll
            for (int u = 3; u >= 0; u--) {
                float f = (float)f4[u], z = (float)z4[u];
                W = f * W + (1.f - f) * z;
                P *= f;
            }
        }
    }
    PW[(((size_t)(dir * 8 + b)) * NCHUNK + s) * 256 + d] = make_float2(P, W);
}

// ---------------------------------------------------------------------------
// scan_seq (phase B): sequential scan over NCHUNK=128 chunks.
__global__ void scan_seq(const float2* __restrict__ PW, float* __restrict__ C0) {
    const int c = threadIdx.x;
    const int dir = blockIdx.x >> 3, b = blockIdx.x & 7;
    const size_t base = ((size_t)(dir * 8 + b)) * NCHUNK * 256 + c;
    float cc = 0.f;
    if (dir == 0) {
#pragma unroll 16
        for (int s = 0; s < NCHUNK; s++) {
            float2 pw = PW[base + (size_t)s * 256];
            C0[base + (size_t)s * 256] = cc;
            cc = pw.x * cc + pw.y;
        }
    } else {
#pragma unroll 16
        for (int s = NCHUNK - 1; s >= 0; s--) {
            float2 pw = PW[base + (size_t)s * 256];
            C0[base + (size_t)s * 256] = cc;
            cc = pw.x * cc + pw.y;
        }
    }
}

// ---------------------------------------------------------------------------
// scan_final (phase C): thread = one channel, block = one (chunk,b,dir).
// Replays the chunk from C0; h values round-trip through a 4KB LDS tile per
// 4-t group so the global store is [t][ch]-contiguous float4 per lane.
__global__ void scan_final(const _Float16* __restrict__ gates,
                           const float* __restrict__ C0,
                           float* __restrict__ out) {
    __shared__ float hbuf[4][256];
    const int d = threadIdx.x;
    const int s = blockIdx.x, b = blockIdx.y, dir = blockIdx.z;
    const int onf = gate_noff(dir * 768 + d);
    const int ono = gate_noff(dir * 768 + 256 + d);
    const int onz = gate_noff(dir * 768 + 512 + d);
    float c = C0[(((size_t)(dir * 8 + b)) * NCHUNK + s) * 256 + d];
    float* ob = out + (size_t)(b * L_) * (2 * DOUT) + dir * DOUT;
    float* lasth = out + (size_t)B_ * L_ * (2 * DOUT);
    float* lastc = lasth + B_ * (2 * DOUT);
    const int tl = d >> 6, cl = (d & 63) * 4;    // output-store mapping

    for (int gg = 0; gg < 8; gg++) {
        int gi = (dir == 0) ? gg : 7 - gg;
        int t = s * CHUNK + gi * 4;
        int ot = gate_toff(b, t);
        half4 f4 = *(const half4*)(gates + ot + onf);
        half4 o4 = *(const half4*)(gates + ot + ono);
        half4 z4 = *(const half4*)(gates + ot + onz);
        float h[4];
        if (dir == 0) {
#pragma unroll
            for (int u = 0; u < 4; u++) {
                float f = (float)f4[u], z = (float)z4[u];
                c = f * c + (1.f - f) * z;
                h[u] = c * (float)o4[u];
            }
            if (s == NCHUNK - 1 && gi == 7) {
                lasth[b * 2 * DOUT + d] = h[3];
                lastc[b * 2 * DOUT + d] = c;
            }
        } else {
#pragma unroll
            for (int u = 3; u >= 0; u--) {
                float f = (float)f4[u], z = (float)z4[u];
                c = f * c + (1.f - f) * z;
                h[u] = c * (float)o4[u];
                if (u == 3 && s == NCHUNK - 1 && gi == 7) {
                    lasth[b * 2 * DOUT + DOUT + d] = h[3];
                    lastc[b * 2 * DOUT + DOUT + d] = c;
                }
            }
        }
        hbuf[0][d] = h[0];
        hbuf[1][d] = h[1];
        hbuf[2][d] = h[2];
        hbuf[3][d] = h[3];
        __syncthreads();
        *(float4*)&ob[(size_t)(t + tl) * (2 * DOUT) + cl] = *(float4*)&hbuf[tl][cl];
        __syncthreads();
    }
}

// ---------------------------------------------------------------------------
extern "C" void kernel_launch(void* const* d_in, const int* in_sizes, int n_in,
                              void* d_out, int out_size, void* d_ws, size_t ws_size,
                              hipStream_t stream) {
    const float* x   = (const float*)d_in[0];
    // d_in[1] = lengths (unused by the reference computation)
    const float* Wf  = (const float*)d_in[2];
    const float* bfv = (const float*)d_in[3];
    const float* Wb  = (const float*)d_in[4];
    const float* bbv = (const float*)d_in[5];

    char* ws = (char*)d_ws;
    // Workspace layout (bytes):
    //   Xp    bf16  B*(L+2)*256          = 16,785,408   (offset 0; dead after GEMM)
    //   Wc    bf16  1536*768             =  2,359,296   (offset 16,785,408)
    //   bc    f32   1536                 =      6,144   (offset 19,144,704)
    //   gates fp16  B*L*1536             = 100,663,296  (offset 19,150,848, native layout)
    //   PW    f32x2 2*8*128*256          =  4,194,304   (offset 0 — reuses Xp)
    //   C0    f32   2*8*128*256          =  2,097,152   (offset 4,194,304 — reuses Xp)
    unsigned short* Xp    = (unsigned short*)(ws);
    unsigned short* Wc    = (unsigned short*)(ws + 16785408);
    float*          bc    = (float*)(ws + 19144704);
    _Float16*       gates = (_Float16*)(ws + 19150848);
    float2*         PW    = (float2*)(ws);              // reuse Xp region
    float*          C0    = (float*)(ws + 4194304);     // reuse Xp region
    float*          out   = (float*)d_out;

    prep_all<<<NXB + NWB, 256, 0, stream>>>(x, Xp, Wf, bfv, Wb, bbv, Wc, bc);
    gemm_gates<<<1536, 512, 0, stream>>>(Xp, Wc, bc, gates);
    scan_chunks<<<dim3(NCHUNK, B_, 2), 256, 0, stream>>>(gates, PW);
    scan_seq<<<16, 256, 0, stream>>>(PW, C0);
    scan_final<<<dim3(NCHUNK, B_, 2), 256, 0, stream>>>(gates, C0, out);
}